// Round 15
// baseline (234.185 us; speedup 1.0000x reference)
//
#include <hip/hip_runtime.h>
#include <hip/hip_bf16.h>

#define NEG_SLOPE 0.2f
#define BINB 512
#define BIN_CHUNK 2048
#define MAXBKT 2048

typedef __attribute__((ext_vector_type(8))) short bf16x8;
typedef __attribute__((ext_vector_type(4))) float f32x4;

__device__ __forceinline__ unsigned short bf16rne(float x) {
    unsigned int u = __float_as_uint(x);
    u += 0x7fffu + ((u >> 16) & 1u);
    return (unsigned short)(u >> 16);
}
__device__ __forceinline__ unsigned int pk2bf16(float lo, float hi) {
    return ((unsigned int)bf16rne(hi) << 16) | bf16rne(lo);
}

// ---------------------------------------------------------------------------
__global__ void init_kernel(int* __restrict__ bucket_cnt, float* __restrict__ ea_sums,
                            float* __restrict__ pooled) {
    int t = threadIdx.x;
    for (int i = t; i < BINB; i += 256) bucket_cnt[i] = 0;
    if (t < 16) ea_sums[t] = 0.f;
    for (int i = t; i < 2048; i += 256) pooled[i] = 0.f;
}

// ---------------------------------------------------------------------------
__global__ __launch_bounds__(256) void ea_colsum(const float* __restrict__ ea,
                                                 float* __restrict__ sums, int E_) {
    int j = threadIdx.x & 15, rl = threadIdx.x >> 4;
    float acc = 0.f;
    for (long long r = (long long)blockIdx.x * 16 + rl; r < E_; r += (long long)gridDim.x * 16)
        acc += ea[r * 16 + j];
    __shared__ float red[256];
    red[rl * 16 + j] = acc;
    __syncthreads();
    if (threadIdx.x < 16) {
        float s = 0.f;
#pragma unroll
        for (int i = 0; i < 16; i++) s += red[i * 16 + threadIdx.x];
        atomicAdd(&sums[threadIdx.x], s);
    }
}

// ---------------------------------------------------------------------------
__global__ __launch_bounds__(256) void bin_count(const int* __restrict__ dst,
                                                 int* __restrict__ bucket_cnt,
                                                 int* __restrict__ blockbase,
                                                 int E_, int EN_, int npb) {
    __shared__ int hist[BINB];
    int tid = threadIdx.x;
    for (int i = tid; i < BINB; i += 256) hist[i] = 0;
    __syncthreads();
    int base = blockIdx.x * BIN_CHUNK;
    int lim = min(base + BIN_CHUNK, EN_);
    for (int e = base + tid; e < lim; e += 256) {
        int d = (e < E_) ? dst[e] : e - E_;
        atomicAdd(&hist[d / npb], 1);
    }
    __syncthreads();
    for (int b = tid; b < BINB; b += 256) {
        int c = hist[b];
        blockbase[blockIdx.x * BINB + b] = (c > 0) ? atomicAdd(&bucket_cnt[b], c) : 0;
    }
}

__global__ __launch_bounds__(512) void bucket_scan(const int* __restrict__ bucket_cnt,
                                                   int* __restrict__ bucket_off,
                                                   int* __restrict__ rowptr, int n, int total) {
    __shared__ int tmp[BINB];
    int t = threadIdx.x;
    tmp[t] = bucket_cnt[t];
    __syncthreads();
    for (int off = 1; off < BINB; off <<= 1) {
        int v = (t >= off) ? tmp[t - off] : 0;
        __syncthreads();
        tmp[t] += v;
        __syncthreads();
    }
    bucket_off[t] = (t == 0) ? 0 : tmp[t - 1];
    if (t == 0) rowptr[n] = total;
}

// bin_se.y packs: e (bits 0..19) | (d - bucket_base) << 20
__global__ __launch_bounds__(256) void bin_scatter(const int* __restrict__ src,
                                                   const int* __restrict__ dst,
                                                   const int* __restrict__ bucket_off,
                                                   const int* __restrict__ blockbase,
                                                   int2* __restrict__ bin_se,
                                                   int E_, int EN_, int npb) {
    __shared__ int hist[BINB];
    int tid = threadIdx.x;
    for (int i = tid; i < BINB; i += 256) hist[i] = 0;
    __syncthreads();
    int base = blockIdx.x * BIN_CHUNK;
    int lim = min(base + BIN_CHUNK, EN_);
    for (int e = base + tid; e < lim; e += 256) {
        int s, d;
        if (e < E_) { s = src[e]; d = dst[e]; } else { s = d = e - E_; }
        int b = d / npb;
        int rank = atomicAdd(&hist[b], 1);
        int pos = bucket_off[b] + blockbase[blockIdx.x * BINB + b] + rank;
        bin_se[pos] = make_int2(s, e | ((d - b * npb) << 20));
    }
}

__global__ __launch_bounds__(256) void csr_build(const int* __restrict__ bucket_off,
                                                 const int2* __restrict__ bin_se,
                                                 int* __restrict__ csr_s,
                                                 int* __restrict__ csr_e,
                                                 int* __restrict__ row_of,
                                                 int* __restrict__ rowptr,
                                                 int n, int EN_, int npb) {
    __shared__ int pk[MAXBKT];
    __shared__ int sv[MAXBKT];
    __shared__ int cnts[256];
    int b = blockIdx.x;
    int tid = threadIdx.x;
    int nb = b * npb;
    int nn = min(npb, n - nb);
    if (nn <= 0) return;
    int off0 = bucket_off[b];
    int off1 = (b == BINB - 1) ? EN_ : bucket_off[b + 1];
    int cnt = min(off1 - off0, MAXBKT);
    cnts[tid] = 0;
    __syncthreads();
    for (int i = tid; i < cnt; i += 256) {
        int2 se = bin_se[off0 + i];
        sv[i] = se.x;
        pk[i] = se.y;
        atomicAdd(&cnts[se.y >> 20], 1);
    }
    __syncthreads();
    for (int off = 1; off < 256; off <<= 1) {
        int v = (tid >= off) ? cnts[tid - off] : 0;
        __syncthreads();
        cnts[tid] += v;
        __syncthreads();
    }
    int excl = (tid == 0) ? 0 : cnts[tid - 1];
    __syncthreads();
    cnts[tid] = off0 + excl;
    if (tid < nn) rowptr[nb + tid] = off0 + excl;
    __syncthreads();
    for (int i = tid; i < cnt; i += 256) {
        int y = pk[i];
        int dloc = y >> 20;
        int pos = atomicAdd(&cnts[dloc], 1);
        csr_s[pos] = sv[i];
        csr_e[pos] = y & 0xFFFFF;
        row_of[pos] = nb + dloc;
    }
}

// ---------------------------------------------------------------------------
__global__ __launch_bounds__(256) void wprep(
    const float* __restrict__ W1, const float* __restrict__ W2,
    const float* __restrict__ We1, const float* __restrict__ ate1,
    const float* __restrict__ We2, const float* __restrict__ ate2,
    const float* __restrict__ ea_sums, float invE,
    unsigned short* __restrict__ Wt1, unsigned short* __restrict__ Wt2,
    float* __restrict__ V1, float* __restrict__ V2,
    float* __restrict__ aes1, float* __restrict__ aes2,
    const int* __restrict__ batch, int* __restrict__ gstart, int n) {
    int b = blockIdx.x, tid = threadIdx.x;
    if (b < 64) {
        const float* W = (b < 32) ? W1 : W2;
        unsigned short* Wt = (b < 32) ? Wt1 : Wt2;
        int base = (b & 31) * 512;
#pragma unroll
        for (int r = 0; r < 2; r++) {
            int flat = base + r * 256 + tid;
            int nn = flat >> 7, k = flat & 127;
            Wt[nn * 128 + k] = bf16rne(W[k * 128 + nn]);
        }
    } else if (b == 64) {
        __shared__ float V1s[64], V2s[64];
        if (tid < 64) {
            int dd = tid >> 2, h = tid & 3;
            float s = 0.f;
            for (int c = 0; c < 32; c++) s += We1[dd * 128 + h * 32 + c] * ate1[h * 32 + c];
            V1[dd * 4 + h] = s; V1s[dd * 4 + h] = s;
        } else if (tid < 128) {
            int t = tid - 64, dd = t >> 2, h = t & 3;
            float s = 0.f;
            for (int c = 0; c < 32; c++) s += We2[dd * 128 + h * 32 + c] * ate2[h * 32 + c];
            V2[dd * 4 + h] = s; V2s[dd * 4 + h] = s;
        }
        __syncthreads();
        if (tid < 4) {
            float s = 0.f;
            for (int dd = 0; dd < 16; dd++) s += ea_sums[dd] * invE * V1s[dd * 4 + tid];
            aes1[tid] = s;
        } else if (tid >= 64 && tid < 68) {
            int h = tid - 64;
            float s = 0.f;
            for (int dd = 0; dd < 16; dd++) s += ea_sums[dd] * invE * V2s[dd * 4 + h];
            aes2[h] = s;
        }
    } else {
        int g = tid;
        if (g > 64) return;
        if (g == 64) { gstart[64] = n; return; }
        int lo = 0, hi = n;
        while (lo < hi) {
            int mid = (lo + hi) >> 1;
            if (batch[mid] < g) lo = mid + 1; else hi = mid;
        }
        gstart[g] = lo;
    }
}

// ---------------------------------------------------------------------------
template<bool BF16IN>
__global__ __launch_bounds__(256) void gemm_att_mfma(
    const void* __restrict__ Xin, const unsigned short* __restrict__ Wtg,
    const float* __restrict__ att_s, const float* __restrict__ att_d,
    unsigned short* __restrict__ XWb, float* __restrict__ a_s,
    float* __restrict__ a_d, int n) {
    __shared__ unsigned short Wt[128][136];
    __shared__ unsigned short Xs[4][16][136];
    __shared__ float attsL[128], attdL[128];

    int tid = threadIdx.x;
    int w = tid >> 6, lane = tid & 63;
    int l15 = lane & 15, rgrp = lane >> 4;

    if (tid < 128) { attsL[tid] = att_s[tid]; attdL[tid] = att_d[tid]; }

#pragma unroll
    for (int it = 0; it < 8; it++) {
        int flat = it * 256 + tid;
        int nn = flat >> 4, kq = flat & 15;
        *(uint4*)&Wt[nn][kq * 8] = *(const uint4*)(Wtg + nn * 128 + kq * 8);
    }

    int r0 = blockIdx.x * 64 + w * 16;
    {
        int rr = lane >> 2;
        int row = r0 + rr;
        int c0 = (lane & 3) * 32;
        if (!BF16IN) {
            const float* Xf = (const float*)Xin;
#pragma unroll
            for (int q = 0; q < 8; q++) {
                int c = c0 + q * 4;
                float4 v = make_float4(0.f, 0.f, 0.f, 0.f);
                if (row < n) v = *(const float4*)(Xf + (size_t)row * 128 + c);
                uint2 p;
                p.x = pk2bf16(v.x, v.y);
                p.y = pk2bf16(v.z, v.w);
                *(uint2*)&Xs[w][rr][c] = p;
            }
        } else {
            const unsigned short* Xb = (const unsigned short*)Xin;
#pragma unroll
            for (int q = 0; q < 4; q++) {
                int c = c0 + q * 8;
                uint4 v = make_uint4(0u, 0u, 0u, 0u);
                if (row < n) v = *(const uint4*)(Xb + (size_t)row * 128 + c);
                *(uint4*)&Xs[w][rr][c] = v;
            }
        }
    }
    __syncthreads();

    f32x4 acc[8];
#pragma unroll
    for (int ct = 0; ct < 8; ct++) acc[ct] = (f32x4){0.f, 0.f, 0.f, 0.f};

#pragma unroll
    for (int kt = 0; kt < 4; kt++) {
        int k0 = kt * 32 + rgrp * 8;
        bf16x8 a = *(const bf16x8*)&Xs[w][l15][k0];
#pragma unroll
        for (int ct = 0; ct < 8; ct++) {
            bf16x8 b = *(const bf16x8*)&Wt[ct * 16 + l15][k0];
            acc[ct] = __builtin_amdgcn_mfma_f32_16x16x32_bf16(a, b, acc[ct], 0, 0, 0);
        }
    }

    float ar[8], br[8];
#pragma unroll
    for (int ct = 0; ct < 8; ct++) {
        ar[ct] = attsL[ct * 16 + l15];
        br[ct] = attdL[ct * 16 + l15];
    }
#pragma unroll
    for (int i = 0; i < 4; i++) {
        float ps[4], pd[4];
#pragma unroll
        for (int h = 0; h < 4; h++) {
            ps[h] = acc[2 * h][i] * ar[2 * h] + acc[2 * h + 1][i] * ar[2 * h + 1];
            pd[h] = acc[2 * h][i] * br[2 * h] + acc[2 * h + 1][i] * br[2 * h + 1];
        }
#pragma unroll
        for (int off = 1; off < 16; off <<= 1) {
#pragma unroll
            for (int h = 0; h < 4; h++) {
                ps[h] += __shfl_xor(ps[h], off);
                pd[h] += __shfl_xor(pd[h], off);
            }
        }
        if (l15 == 0) {
            int row = r0 + rgrp * 4 + i;
            if (row < n) {
                *(float4*)(a_s + (size_t)row * 4) = make_float4(ps[0], ps[1], ps[2], ps[3]);
                *(float4*)(a_d + (size_t)row * 4) = make_float4(pd[0], pd[1], pd[2], pd[3]);
            }
        }
    }

    unsigned short* stage = &Xs[w][0][0];
#pragma unroll
    for (int i = 0; i < 4; i++) {
        int row = rgrp * 4 + i;
#pragma unroll
        for (int ct = 0; ct < 8; ct++)
            stage[row * 128 + ct * 16 + l15] = bf16rne(acc[ct][i]);
    }
#pragma unroll
    for (int p = 0; p < 4; p++) {
        int fo = p * 1024 + lane * 16;
        int row = fo >> 8;
        int colb = fo & 255;
        uint4 v = *(const uint4*)((const char*)stage + fo);
        int grow = r0 + row;
        if (grow < n)
            *(uint4*)((char*)XWb + (size_t)grow * 256 + colb) = v;
    }
}

// ---------------------------------------------------------------------------
// Layer-1 alpha: streams ea once; writes csr_alpha (L1 alpha) and aeb2
// (L2 edge term) as packed bf16x4 (8B/position, halves edge-array traffic).
__global__ __launch_bounds__(256) void alpha1_fused(
    const int* __restrict__ csr_s, const int* __restrict__ csr_e,
    const int* __restrict__ row_of, const float* __restrict__ ea,
    const float* __restrict__ V1, const float* __restrict__ V2,
    const float* __restrict__ aes1, const float* __restrict__ aes2,
    const float* __restrict__ a_s, const float* __restrict__ a_d,
    uint2* __restrict__ csr_alpha, uint2* __restrict__ aeb2, int E_, int EN_) {
    __shared__ float V1l[64], V2l[64], a1l[4], a2l[4];
    int tid = threadIdx.x;
    if (tid < 64) { V1l[tid] = V1[tid]; V2l[tid] = V2[tid]; }
    if (tid < 4) { a1l[tid] = aes1[tid]; a2l[tid] = aes2[tid]; }
    __syncthreads();
    int i = blockIdx.x * 256 + tid;
    if (i >= EN_) return;
    int s = csr_s[i], e = csr_e[i], d = row_of[i];
    float ae1[4], ae2[4];
    if (e < E_) {
#pragma unroll
        for (int h = 0; h < 4; h++) { ae1[h] = 0.f; ae2[h] = 0.f; }
        const float4* er = (const float4*)(ea + (size_t)e * 16);
#pragma unroll
        for (int q = 0; q < 4; q++) {
            float4 v = er[q];
#pragma unroll
            for (int h = 0; h < 4; h++) {
                ae1[h] += v.x * V1l[(q * 4 + 0) * 4 + h] + v.y * V1l[(q * 4 + 1) * 4 + h] +
                          v.z * V1l[(q * 4 + 2) * 4 + h] + v.w * V1l[(q * 4 + 3) * 4 + h];
                ae2[h] += v.x * V2l[(q * 4 + 0) * 4 + h] + v.y * V2l[(q * 4 + 1) * 4 + h] +
                          v.z * V2l[(q * 4 + 2) * 4 + h] + v.w * V2l[(q * 4 + 3) * 4 + h];
            }
        }
    } else {
#pragma unroll
        for (int h = 0; h < 4; h++) { ae1[h] = a1l[h]; ae2[h] = a2l[h]; }
    }
    float4 asv = *(const float4*)(a_s + (size_t)s * 4);
    float4 adv = *(const float4*)(a_d + (size_t)d * 4);
    float o0 = asv.x + adv.x + ae1[0];
    float o1 = asv.y + adv.y + ae1[1];
    float o2 = asv.z + adv.z + ae1[2];
    float o3 = asv.w + adv.w + ae1[3];
    o0 = o0 > 0.f ? o0 : NEG_SLOPE * o0;
    o1 = o1 > 0.f ? o1 : NEG_SLOPE * o1;
    o2 = o2 > 0.f ? o2 : NEG_SLOPE * o2;
    o3 = o3 > 0.f ? o3 : NEG_SLOPE * o3;
    uint2 pa;
    pa.x = pk2bf16(o0, o1);
    pa.y = pk2bf16(o2, o3);
    csr_alpha[i] = pa;
    uint2 pe;
    pe.x = pk2bf16(ae2[0], ae2[1]);
    pe.y = pk2bf16(ae2[2], ae2[3]);
    aeb2[i] = pe;
}

// ---------------------------------------------------------------------------
// Wave-per-dst softmax-gather (round-12 structure): 16-edge main chunks +
// predicated 4-group tail; 2 edges per VMEM instruction; bf16 alpha arrays.
template<int MODE>
__global__ __launch_bounds__(256) void dst_aggregate(
    const int* __restrict__ rowptr, const int* __restrict__ csr_s,
    const unsigned int* __restrict__ alpha_b, const float* __restrict__ as2,
    const float* __restrict__ ad2, const uint2* __restrict__ XW2,
    const float* __restrict__ bias, unsigned int* __restrict__ OUT, int n) {
    int wv = threadIdx.x >> 6, lane = threadIdx.x & 63;
    int d = blockIdx.x * 4 + wv;
    if (d >= n) return;
    int h = lane >> 4, j = lane & 15;      // staging coords
    int half = lane >> 5, u = lane & 31;   // consumer coords
    int hc16 = (u >> 3) << 4;              // consumer head * 16
    int hsel = h >> 1, hodd = h & 1;
    int beg = rowptr[d], end = rowptr[d + 1];

    float advh = 0.f;
    if (MODE == 0) advh = ad2[(size_t)d * 4 + h];

    float a0 = 0.f, a1 = 0.f, a2 = 0.f, a3 = 0.f;
    float den = 0.f;

    int i = beg;
    for (; i + 16 <= end; i += 16) {
        int i0 = i + j;
        int sreg = csr_s[i0];
        unsigned int au = alpha_b[(size_t)i0 * 2 + hsel];
        float a = __uint_as_float(hodd ? (au & 0xffff0000u) : (au << 16));
        if (MODE == 0) {
            a += as2[(size_t)sreg * 4 + h] + advh;
            a = a > 0.f ? a : NEG_SLOPE * a;
        }
        float w = __expf(a);
        den += w;
#pragma unroll
        for (int m = 0; m < 8; m++) {
            int k = 2 * m + half;
            int s = __shfl(sreg, k);
            float wk = __shfl(w, hc16 + k);
            uint2 v = XW2[(size_t)s * 32 + u];
            a0 += wk * __uint_as_float(v.x << 16);
            a1 += wk * __uint_as_float(v.x & 0xffff0000u);
            a2 += wk * __uint_as_float(v.y << 16);
            a3 += wk * __uint_as_float(v.y & 0xffff0000u);
        }
    }
    int cnt = end - i;
    if (cnt > 0) {
        float w = 0.f; int sreg = 0;
        if (j < cnt) {
            int i0 = i + j;
            sreg = csr_s[i0];
            unsigned int au = alpha_b[(size_t)i0 * 2 + hsel];
            float a = __uint_as_float(hodd ? (au & 0xffff0000u) : (au << 16));
            if (MODE == 0) {
                a += as2[(size_t)sreg * 4 + h] + advh;
                a = a > 0.f ? a : NEG_SLOPE * a;
            }
            w = __expf(a);
        }
        den += w;
        for (int k0 = 0; k0 < cnt; k0 += 4) {
#pragma unroll
            for (int mm = 0; mm < 2; mm++) {
                int k = k0 + 2 * mm + half;
                int kc = k & 15;
                int s = __shfl(sreg, kc);
                float wk = __shfl(w, hc16 + kc);
                if (k >= cnt) wk = 0.f;
                uint2 v = XW2[(size_t)s * 32 + u];
                a0 += wk * __uint_as_float(v.x << 16);
                a1 += wk * __uint_as_float(v.x & 0xffff0000u);
                a2 += wk * __uint_as_float(v.y << 16);
                a3 += wk * __uint_as_float(v.y & 0xffff0000u);
            }
        }
    }
    a0 += __shfl_xor(a0, 32);
    a1 += __shfl_xor(a1, 32);
    a2 += __shfl_xor(a2, 32);
    a3 += __shfl_xor(a3, 32);
    den += __shfl_xor(den, 1);
    den += __shfl_xor(den, 2);
    den += __shfl_xor(den, 4);
    den += __shfl_xor(den, 8);
    float denc = __shfl(den, hc16);
    float inv = 1.f / (denc + 1e-16f);
    if (half == 0) {
        int c0 = u * 4;
        float o0 = a0 * inv, o1 = a1 * inv, o2 = a2 * inv, o3 = a3 * inv;
        if (MODE == 1) {
            float4 bb = *(const float4*)(bias + c0);
            o0 = fmaxf(o0 + bb.x, 0.f);
            o1 = fmaxf(o1 + bb.y, 0.f);
            o2 = fmaxf(o2 + bb.z, 0.f);
            o3 = fmaxf(o3 + bb.w, 0.f);
        }
        uint2 pv;
        pv.x = pk2bf16(o0, o1);
        pv.y = pk2bf16(o2, o3);
        *((uint2*)OUT + (size_t)d * 32 + u) = pv;
    }
}

// ---------------------------------------------------------------------------
#define POOL_SPLITS 8
__global__ __launch_bounds__(256) void pool_kernel(const unsigned int* __restrict__ B,
                                                   const int* __restrict__ gstart,
                                                   float* __restrict__ pooled) {
    int g = blockIdx.x / POOL_SPLITS, sp = blockIdx.x % POOL_SPLITS;
    int lo = gstart[g], hi = gstart[g + 1];
    int cnt = hi - lo;
    int per = (cnt + POOL_SPLITS - 1) / POOL_SPLITS;
    int s0 = lo + sp * per;
    int s1 = min(s0 + per, hi);
    int jj = threadIdx.x & 15, rl = threadIdx.x >> 4;
    float ax = 0.f, ay = 0.f;
    for (int node = s0 + rl; node < s1; node += 16) {
        const unsigned int* r = B + (size_t)node * 64;
#pragma unroll
        for (int h = 0; h < 4; h++) {
            unsigned int v = r[h * 16 + jj];
            ax += __uint_as_float(v << 16);
            ay += __uint_as_float(v & 0xffff0000u);
        }
    }
    __shared__ float redx[16][16], redy[16][16];
    redx[rl][jj] = ax * 0.25f;
    redy[rl][jj] = ay * 0.25f;
    __syncthreads();
    if (threadIdx.x < 16) {
        float sx = 0.f, sy = 0.f;
#pragma unroll
        for (int i = 0; i < 16; i++) { sx += redx[i][threadIdx.x]; sy += redy[i][threadIdx.x]; }
        atomicAdd(&pooled[g * 32 + 2 * threadIdx.x], sx);
        atomicAdd(&pooled[g * 32 + 2 * threadIdx.x + 1], sy);
    }
}

__global__ void mlp_kernel(const float* __restrict__ pooled, const int* __restrict__ gstart,
                           const float* __restrict__ b2,
                           const float* __restrict__ W3, const float* __restrict__ b3,
                           const float* __restrict__ W4, const float* __restrict__ b4,
                           float* __restrict__ out) {
    int g = blockIdx.x;
    int c = threadIdx.x;
    __shared__ float pm[32];
    __shared__ float t[32];
    int cnt = gstart[g + 1] - gstart[g];
    if (c < 32) {
        float m = 0.f;
        if (cnt > 0) m = pooled[g * 32 + c] / (float)cnt + b2[c];
        pm[c] = m;
    }
    __syncthreads();
    if (c < 32) {
        float s = b3[c];
        for (int k = 0; k < 32; k++) s += pm[k] * W3[k * 32 + c];
        t[c] = fmaxf(s, 0.f);
    }
    __syncthreads();
    if (c < 2) {
        float o = b4[c];
        for (int k = 0; k < 32; k++) o += t[k] * W4[k * 2 + c];
        out[g * 2 + c] = o;
    }
}

// ---------------------------------------------------------------------------
extern "C" void kernel_launch(void* const* d_in, const int* in_sizes, int n_in,
                              void* d_out, int out_size, void* d_ws, size_t ws_size,
                              hipStream_t stream) {
    const float* x    = (const float*)d_in[0];
    const int*   eidx = (const int*)d_in[1];
    const float* ea   = (const float*)d_in[2];
    const int*   batch= (const int*)d_in[3];
    const float* W1   = (const float*)d_in[4];
    const float* as1  = (const float*)d_in[5];
    const float* ad1  = (const float*)d_in[6];
    const float* We1  = (const float*)d_in[7];
    const float* ate1 = (const float*)d_in[8];
    const float* b1   = (const float*)d_in[9];
    const float* W2   = (const float*)d_in[10];
    const float* as2  = (const float*)d_in[11];
    const float* ad2  = (const float*)d_in[12];
    const float* We2  = (const float*)d_in[13];
    const float* ate2 = (const float*)d_in[14];
    const float* b2   = (const float*)d_in[15];
    const float* W3   = (const float*)d_in[16];
    const float* b3   = (const float*)d_in[17];
    const float* W4   = (const float*)d_in[18];
    const float* b4   = (const float*)d_in[19];

    const int N_ = in_sizes[0] / 128;
    const int E_ = in_sizes[1] / 2;
    const int EN = E_ + N_;
    const int* srcp = eidx;
    const int* dstp = eidx + E_;
    const int npb = (N_ + BINB - 1) / BINB;
    const int nbk = (EN + BIN_CHUNK - 1) / BIN_CHUNK;

    char* w = (char*)d_ws;
    size_t off = 0;
    auto alloc = [&](size_t bytes) -> void* {
        void* p = w + off;
        off = (off + bytes + 255) & ~(size_t)255;
        return p;
    };
    unsigned short* A   = (unsigned short*)alloc((size_t)N_ * 128 * 2);
    unsigned short* Bb16= (unsigned short*)alloc((size_t)N_ * 128 * 2);
    uint2* csr_alpha = (uint2*)alloc((size_t)EN * 8);
    uint2* aeb2      = (uint2*)alloc((size_t)EN * 8);
    int*   csr_s     = (int*)alloc((size_t)EN * 4);
    int*   csr_e     = (int*)alloc((size_t)EN * 4);
    int*   row_of    = (int*)alloc((size_t)EN * 4);
    int2*  bin_se    = (int2*)alloc((size_t)EN * 8);
    int*   rowptr    = (int*)alloc((size_t)(N_ + 1) * 4);
    int*   bucket_cnt= (int*)alloc(BINB * 4);
    int*   bucket_off= (int*)alloc(BINB * 4);
    int*   blockbase = (int*)alloc((size_t)nbk * BINB * 4);
    unsigned short* Wt1g = (unsigned short*)alloc(16384 * 2);
    unsigned short* Wt2g = (unsigned short*)alloc(16384 * 2);
    float* a_s       = (float*)alloc((size_t)N_ * 16);
    float* a_d       = (float*)alloc((size_t)N_ * 16);
    float* ea_sums   = (float*)alloc(64);
    float* V1        = (float*)alloc(256);
    float* V2        = (float*)alloc(256);
    float* aes1      = (float*)alloc(16);
    float* aes2      = (float*)alloc(16);
    float* pooled    = (float*)alloc(64 * 32 * 4);
    int*   gstart    = (int*)alloc(65 * 4);

    init_kernel<<<1, 256, 0, stream>>>(bucket_cnt, ea_sums, pooled);
    ea_colsum<<<1024, 256, 0, stream>>>(ea, ea_sums, E_);
    bin_count<<<nbk, 256, 0, stream>>>(dstp, bucket_cnt, blockbase, E_, EN, npb);
    bucket_scan<<<1, BINB, 0, stream>>>(bucket_cnt, bucket_off, rowptr, N_, EN);
    wprep<<<66, 256, 0, stream>>>(W1, W2, We1, ate1, We2, ate2, ea_sums,
                                  1.0f / (float)E_, Wt1g, Wt2g, V1, V2, aes1, aes2,
                                  batch, gstart, N_);
    bin_scatter<<<nbk, 256, 0, stream>>>(srcp, dstp, bucket_off, blockbase,
                                         bin_se, E_, EN, npb);
    csr_build<<<BINB, 256, 0, stream>>>(bucket_off, bin_se, csr_s, csr_e,
                                        row_of, rowptr, N_, EN, npb);

    int gblk = (N_ + 63) / 64;

    // ---- layer 1 ----
    gemm_att_mfma<false><<<gblk, 256, 0, stream>>>(x, Wt1g, as1, ad1, A, a_s, a_d, N_);
    alpha1_fused<<<(EN + 255) / 256, 256, 0, stream>>>(csr_s, csr_e, row_of, ea,
                                                       V1, V2, aes1, aes2, a_s, a_d,
                                                       csr_alpha, aeb2, E_, EN);
    dst_aggregate<1><<<(N_ + 3) / 4, 256, 0, stream>>>(rowptr, csr_s,
                                                       (const unsigned int*)csr_alpha,
                                                       nullptr, nullptr,
                                                       (const uint2*)A, b1,
                                                       (unsigned int*)Bb16, N_);

    // ---- layer 2 ----
    gemm_att_mfma<true><<<gblk, 256, 0, stream>>>(Bb16, Wt2g, as2, ad2, A, a_s, a_d, N_);
    dst_aggregate<0><<<(N_ + 3) / 4, 256, 0, stream>>>(rowptr, csr_s,
                                                       (const unsigned int*)aeb2,
                                                       a_s, a_d,
                                                       (const uint2*)A, b2,
                                                       (unsigned int*)Bb16, N_);
    pool_kernel<<<64 * POOL_SPLITS, 256, 0, stream>>>((const unsigned int*)Bb16,
                                                      gstart, pooled);

    // ---- graph MLP ----
    mlp_kernel<<<64, 64, 0, stream>>>(pooled, gstart, b2, W3, b3, W4, b4, (float*)d_out);
}

// Round 16
// 225.119 us; speedup vs baseline: 1.0403x; 1.0403x over previous
//
#include <hip/hip_runtime.h>
#include <hip/hip_bf16.h>

#define NEG_SLOPE 0.2f
#define BINB 512
#define BIN_CHUNK 2048
#define MAXBKT 2048

typedef __attribute__((ext_vector_type(8))) short bf16x8;
typedef __attribute__((ext_vector_type(4))) float f32x4;

__device__ __forceinline__ unsigned short bf16rne(float x) {
    unsigned int u = __float_as_uint(x);
    u += 0x7fffu + ((u >> 16) & 1u);
    return (unsigned short)(u >> 16);
}
__device__ __forceinline__ unsigned int pk2bf16(float lo, float hi) {
    return ((unsigned int)bf16rne(hi) << 16) | bf16rne(lo);
}

// ---------------------------------------------------------------------------
__global__ void init_kernel(int* __restrict__ bucket_cnt, float* __restrict__ ea_sums,
                            float* __restrict__ pooled) {
    int t = threadIdx.x;
    for (int i = t; i < BINB; i += 256) bucket_cnt[i] = 0;
    if (t < 16) ea_sums[t] = 0.f;
    for (int i = t; i < 2048; i += 256) pooled[i] = 0.f;
}

// ---------------------------------------------------------------------------
__global__ __launch_bounds__(256) void ea_colsum(const float* __restrict__ ea,
                                                 float* __restrict__ sums, int E_) {
    int j = threadIdx.x & 15, rl = threadIdx.x >> 4;
    float acc = 0.f;
    for (long long r = (long long)blockIdx.x * 16 + rl; r < E_; r += (long long)gridDim.x * 16)
        acc += ea[r * 16 + j];
    __shared__ float red[256];
    red[rl * 16 + j] = acc;
    __syncthreads();
    if (threadIdx.x < 16) {
        float s = 0.f;
#pragma unroll
        for (int i = 0; i < 16; i++) s += red[i * 16 + threadIdx.x];
        atomicAdd(&sums[threadIdx.x], s);
    }
}

// ---------------------------------------------------------------------------
__global__ __launch_bounds__(256) void bin_count(const int* __restrict__ dst,
                                                 int* __restrict__ bucket_cnt,
                                                 int* __restrict__ blockbase,
                                                 int E_, int EN_, int npb) {
    __shared__ int hist[BINB];
    int tid = threadIdx.x;
    for (int i = tid; i < BINB; i += 256) hist[i] = 0;
    __syncthreads();
    int base = blockIdx.x * BIN_CHUNK;
    int lim = min(base + BIN_CHUNK, EN_);
    for (int e = base + tid; e < lim; e += 256) {
        int d = (e < E_) ? dst[e] : e - E_;
        atomicAdd(&hist[d / npb], 1);
    }
    __syncthreads();
    for (int b = tid; b < BINB; b += 256) {
        int c = hist[b];
        blockbase[blockIdx.x * BINB + b] = (c > 0) ? atomicAdd(&bucket_cnt[b], c) : 0;
    }
}

__global__ __launch_bounds__(512) void bucket_scan(const int* __restrict__ bucket_cnt,
                                                   int* __restrict__ bucket_off,
                                                   int* __restrict__ rowptr, int n, int total) {
    __shared__ int tmp[BINB];
    int t = threadIdx.x;
    tmp[t] = bucket_cnt[t];
    __syncthreads();
    for (int off = 1; off < BINB; off <<= 1) {
        int v = (t >= off) ? tmp[t - off] : 0;
        __syncthreads();
        tmp[t] += v;
        __syncthreads();
    }
    bucket_off[t] = (t == 0) ? 0 : tmp[t - 1];
    if (t == 0) rowptr[n] = total;
}

// bin_se.y packs: e (bits 0..19) | (d - bucket_base) << 20   (d-nb < 128)
__global__ __launch_bounds__(256) void bin_scatter(const int* __restrict__ src,
                                                   const int* __restrict__ dst,
                                                   const int* __restrict__ bucket_off,
                                                   const int* __restrict__ blockbase,
                                                   int2* __restrict__ bin_se,
                                                   int E_, int EN_, int npb) {
    __shared__ int hist[BINB];
    int tid = threadIdx.x;
    for (int i = tid; i < BINB; i += 256) hist[i] = 0;
    __syncthreads();
    int base = blockIdx.x * BIN_CHUNK;
    int lim = min(base + BIN_CHUNK, EN_);
    for (int e = base + tid; e < lim; e += 256) {
        int s, d;
        if (e < E_) { s = src[e]; d = dst[e]; } else { s = d = e - E_; }
        int b = d / npb;
        int rank = atomicAdd(&hist[b], 1);
        int pos = bucket_off[b] + blockbase[blockIdx.x * BINB + b] + rank;
        bin_se[pos] = make_int2(s, e | ((d - b * npb) << 20));
    }
}

__global__ __launch_bounds__(256) void csr_build(const int* __restrict__ bucket_off,
                                                 const int2* __restrict__ bin_se,
                                                 int2* __restrict__ csr_se,
                                                 int* __restrict__ row_of,
                                                 int* __restrict__ rowptr,
                                                 int n, int EN_, int npb) {
    __shared__ int pk[MAXBKT];
    __shared__ int sv[MAXBKT];
    __shared__ int cnts[256];
    int b = blockIdx.x;
    int tid = threadIdx.x;
    int nb = b * npb;
    int nn = min(npb, n - nb);
    if (nn <= 0) return;
    int off0 = bucket_off[b];
    int off1 = (b == BINB - 1) ? EN_ : bucket_off[b + 1];
    int cnt = min(off1 - off0, MAXBKT);
    cnts[tid] = 0;
    __syncthreads();
    for (int i = tid; i < cnt; i += 256) {
        int2 se = bin_se[off0 + i];
        sv[i] = se.x;
        pk[i] = se.y;
        atomicAdd(&cnts[se.y >> 20], 1);
    }
    __syncthreads();
    for (int off = 1; off < 256; off <<= 1) {
        int v = (tid >= off) ? cnts[tid - off] : 0;
        __syncthreads();
        cnts[tid] += v;
        __syncthreads();
    }
    int excl = (tid == 0) ? 0 : cnts[tid - 1];
    __syncthreads();
    cnts[tid] = off0 + excl;
    if (tid < nn) rowptr[nb + tid] = off0 + excl;
    __syncthreads();
    for (int i = tid; i < cnt; i += 256) {
        int y = pk[i];
        int dloc = y >> 20;
        int pos = atomicAdd(&cnts[dloc], 1);
        csr_se[pos] = make_int2(sv[i], y & 0xFFFFF);
        row_of[pos] = nb + dloc;
    }
}

// ---------------------------------------------------------------------------
__global__ __launch_bounds__(256) void wprep(
    const float* __restrict__ W1, const float* __restrict__ W2,
    const float* __restrict__ We1, const float* __restrict__ ate1,
    const float* __restrict__ We2, const float* __restrict__ ate2,
    const float* __restrict__ ea_sums, float invE,
    unsigned short* __restrict__ Wt1, unsigned short* __restrict__ Wt2,
    float* __restrict__ V1, float* __restrict__ V2,
    float* __restrict__ aes1, float* __restrict__ aes2,
    const int* __restrict__ batch, int* __restrict__ gstart, int n) {
    int b = blockIdx.x, tid = threadIdx.x;
    if (b < 64) {
        const float* W = (b < 32) ? W1 : W2;
        unsigned short* Wt = (b < 32) ? Wt1 : Wt2;
        int base = (b & 31) * 512;
#pragma unroll
        for (int r = 0; r < 2; r++) {
            int flat = base + r * 256 + tid;
            int nn = flat >> 7, k = flat & 127;
            Wt[nn * 128 + k] = bf16rne(W[k * 128 + nn]);
        }
    } else if (b == 64) {
        __shared__ float V1s[64], V2s[64];
        if (tid < 64) {
            int dd = tid >> 2, h = tid & 3;
            float s = 0.f;
            for (int c = 0; c < 32; c++) s += We1[dd * 128 + h * 32 + c] * ate1[h * 32 + c];
            V1[dd * 4 + h] = s; V1s[dd * 4 + h] = s;
        } else if (tid < 128) {
            int t = tid - 64, dd = t >> 2, h = t & 3;
            float s = 0.f;
            for (int c = 0; c < 32; c++) s += We2[dd * 128 + h * 32 + c] * ate2[h * 32 + c];
            V2[dd * 4 + h] = s; V2s[dd * 4 + h] = s;
        }
        __syncthreads();
        if (tid < 4) {
            float s = 0.f;
            for (int dd = 0; dd < 16; dd++) s += ea_sums[dd] * invE * V1s[dd * 4 + tid];
            aes1[tid] = s;
        } else if (tid >= 64 && tid < 68) {
            int h = tid - 64;
            float s = 0.f;
            for (int dd = 0; dd < 16; dd++) s += ea_sums[dd] * invE * V2s[dd * 4 + h];
            aes2[h] = s;
        }
    } else {
        int g = tid;
        if (g > 64) return;
        if (g == 64) { gstart[64] = n; return; }
        int lo = 0, hi = n;
        while (lo < hi) {
            int mid = (lo + hi) >> 1;
            if (batch[mid] < g) lo = mid + 1; else hi = mid;
        }
        gstart[g] = lo;
    }
}

// ---------------------------------------------------------------------------
template<bool BF16IN>
__global__ __launch_bounds__(256) void gemm_att_mfma(
    const void* __restrict__ Xin, const unsigned short* __restrict__ Wtg,
    const float* __restrict__ att_s, const float* __restrict__ att_d,
    unsigned short* __restrict__ XWb, float* __restrict__ a_s,
    float* __restrict__ a_d, int n) {
    __shared__ unsigned short Wt[128][136];
    __shared__ unsigned short Xs[4][16][136];
    __shared__ float attsL[128], attdL[128];

    int tid = threadIdx.x;
    int w = tid >> 6, lane = tid & 63;
    int l15 = lane & 15, rgrp = lane >> 4;

    if (tid < 128) { attsL[tid] = att_s[tid]; attdL[tid] = att_d[tid]; }

#pragma unroll
    for (int it = 0; it < 8; it++) {
        int flat = it * 256 + tid;
        int nn = flat >> 4, kq = flat & 15;
        *(uint4*)&Wt[nn][kq * 8] = *(const uint4*)(Wtg + nn * 128 + kq * 8);
    }

    int r0 = blockIdx.x * 64 + w * 16;
    {
        int rr = lane >> 2;
        int row = r0 + rr;
        int c0 = (lane & 3) * 32;
        if (!BF16IN) {
            const float* Xf = (const float*)Xin;
#pragma unroll
            for (int q = 0; q < 8; q++) {
                int c = c0 + q * 4;
                float4 v = make_float4(0.f, 0.f, 0.f, 0.f);
                if (row < n) v = *(const float4*)(Xf + (size_t)row * 128 + c);
                uint2 p;
                p.x = pk2bf16(v.x, v.y);
                p.y = pk2bf16(v.z, v.w);
                *(uint2*)&Xs[w][rr][c] = p;
            }
        } else {
            const unsigned short* Xb = (const unsigned short*)Xin;
#pragma unroll
            for (int q = 0; q < 4; q++) {
                int c = c0 + q * 8;
                uint4 v = make_uint4(0u, 0u, 0u, 0u);
                if (row < n) v = *(const uint4*)(Xb + (size_t)row * 128 + c);
                *(uint4*)&Xs[w][rr][c] = v;
            }
        }
    }
    __syncthreads();

    f32x4 acc[8];
#pragma unroll
    for (int ct = 0; ct < 8; ct++) acc[ct] = (f32x4){0.f, 0.f, 0.f, 0.f};

#pragma unroll
    for (int kt = 0; kt < 4; kt++) {
        int k0 = kt * 32 + rgrp * 8;
        bf16x8 a = *(const bf16x8*)&Xs[w][l15][k0];
#pragma unroll
        for (int ct = 0; ct < 8; ct++) {
            bf16x8 b = *(const bf16x8*)&Wt[ct * 16 + l15][k0];
            acc[ct] = __builtin_amdgcn_mfma_f32_16x16x32_bf16(a, b, acc[ct], 0, 0, 0);
        }
    }

    float ar[8], br[8];
#pragma unroll
    for (int ct = 0; ct < 8; ct++) {
        ar[ct] = attsL[ct * 16 + l15];
        br[ct] = attdL[ct * 16 + l15];
    }
#pragma unroll
    for (int i = 0; i < 4; i++) {
        float ps[4], pd[4];
#pragma unroll
        for (int h = 0; h < 4; h++) {
            ps[h] = acc[2 * h][i] * ar[2 * h] + acc[2 * h + 1][i] * ar[2 * h + 1];
            pd[h] = acc[2 * h][i] * br[2 * h] + acc[2 * h + 1][i] * br[2 * h + 1];
        }
#pragma unroll
        for (int off = 1; off < 16; off <<= 1) {
#pragma unroll
            for (int h = 0; h < 4; h++) {
                ps[h] += __shfl_xor(ps[h], off);
                pd[h] += __shfl_xor(pd[h], off);
            }
        }
        if (l15 == 0) {
            int row = r0 + rgrp * 4 + i;
            if (row < n) {
                *(float4*)(a_s + (size_t)row * 4) = make_float4(ps[0], ps[1], ps[2], ps[3]);
                *(float4*)(a_d + (size_t)row * 4) = make_float4(pd[0], pd[1], pd[2], pd[3]);
            }
        }
    }

    unsigned short* stage = &Xs[w][0][0];
#pragma unroll
    for (int i = 0; i < 4; i++) {
        int row = rgrp * 4 + i;
#pragma unroll
        for (int ct = 0; ct < 8; ct++)
            stage[row * 128 + ct * 16 + l15] = bf16rne(acc[ct][i]);
    }
#pragma unroll
    for (int p = 0; p < 4; p++) {
        int fo = p * 1024 + lane * 16;
        int row = fo >> 8;
        int colb = fo & 255;
        uint4 v = *(const uint4*)((const char*)stage + fo);
        int grow = r0 + row;
        if (grow < n)
            *(uint4*)((char*)XWb + (size_t)grow * 256 + colb) = v;
    }
}

// ---------------------------------------------------------------------------
__global__ __launch_bounds__(256) void alpha1_fused(
    const int2* __restrict__ csr_se, const int* __restrict__ row_of,
    const float* __restrict__ ea,
    const float* __restrict__ V1, const float* __restrict__ V2,
    const float* __restrict__ aes1, const float* __restrict__ aes2,
    const float* __restrict__ a_s, const float* __restrict__ a_d,
    float* __restrict__ csr_alpha, float* __restrict__ aeb2, int E_, int EN_) {
    __shared__ float V1l[64], V2l[64], a1l[4], a2l[4];
    int tid = threadIdx.x;
    if (tid < 64) { V1l[tid] = V1[tid]; V2l[tid] = V2[tid]; }
    if (tid < 4) { a1l[tid] = aes1[tid]; a2l[tid] = aes2[tid]; }
    __syncthreads();
    int i = blockIdx.x * 256 + tid;
    if (i >= EN_) return;
    int2 se = csr_se[i];
    int s = se.x, e = se.y, d = row_of[i];
    float ae1[4], ae2[4];
    if (e < E_) {
#pragma unroll
        for (int h = 0; h < 4; h++) { ae1[h] = 0.f; ae2[h] = 0.f; }
        const float4* er = (const float4*)(ea + (size_t)e * 16);
#pragma unroll
        for (int q = 0; q < 4; q++) {
            float4 v = er[q];
#pragma unroll
            for (int h = 0; h < 4; h++) {
                ae1[h] += v.x * V1l[(q * 4 + 0) * 4 + h] + v.y * V1l[(q * 4 + 1) * 4 + h] +
                          v.z * V1l[(q * 4 + 2) * 4 + h] + v.w * V1l[(q * 4 + 3) * 4 + h];
                ae2[h] += v.x * V2l[(q * 4 + 0) * 4 + h] + v.y * V2l[(q * 4 + 1) * 4 + h] +
                          v.z * V2l[(q * 4 + 2) * 4 + h] + v.w * V2l[(q * 4 + 3) * 4 + h];
            }
        }
    } else {
#pragma unroll
        for (int h = 0; h < 4; h++) { ae1[h] = a1l[h]; ae2[h] = a2l[h]; }
    }
    float4 asv = *(const float4*)(a_s + (size_t)s * 4);
    float4 adv = *(const float4*)(a_d + (size_t)d * 4);
    float o0 = asv.x + adv.x + ae1[0];
    float o1 = asv.y + adv.y + ae1[1];
    float o2 = asv.z + adv.z + ae1[2];
    float o3 = asv.w + adv.w + ae1[3];
    o0 = o0 > 0.f ? o0 : NEG_SLOPE * o0;
    o1 = o1 > 0.f ? o1 : NEG_SLOPE * o1;
    o2 = o2 > 0.f ? o2 : NEG_SLOPE * o2;
    o3 = o3 > 0.f ? o3 : NEG_SLOPE * o3;
    *(float4*)(csr_alpha + (size_t)i * 4) = make_float4(o0, o1, o2, o3);
    *(float4*)(aeb2 + (size_t)i * 4) = make_float4(ae2[0], ae2[1], ae2[2], ae2[3]);
}

// ---------------------------------------------------------------------------
// Wave-per-dst softmax-gather (round-12 proven variant): 16-edge main chunks
// (exact) + predicated 4-groups tail; 2 edges per VMEM instruction.
template<int MODE>
__global__ __launch_bounds__(256) void dst_aggregate(
    const int* __restrict__ rowptr, const int2* __restrict__ csr_se,
    const float* __restrict__ alpha_arr, const float* __restrict__ as2,
    const float* __restrict__ ad2, const uint2* __restrict__ XW2,
    const float* __restrict__ bias, unsigned int* __restrict__ OUT, int n) {
    int wv = threadIdx.x >> 6, lane = threadIdx.x & 63;
    int d = blockIdx.x * 4 + wv;
    if (d >= n) return;
    int h = lane >> 4, j = lane & 15;      // staging coords
    int half = lane >> 5, u = lane & 31;   // consumer coords
    int hc16 = (u >> 3) << 4;              // consumer head * 16
    int beg = rowptr[d], end = rowptr[d + 1];

    float advh = 0.f;
    if (MODE == 0) advh = ad2[(size_t)d * 4 + h];

    float a0 = 0.f, a1 = 0.f, a2 = 0.f, a3 = 0.f;
    float den = 0.f;

    int i = beg;
    for (; i + 16 <= end; i += 16) {
        int i0 = i + j;
        int sreg = csr_se[i0].x;
        float a = alpha_arr[(size_t)i0 * 4 + h];
        if (MODE == 0) {
            a += as2[(size_t)sreg * 4 + h] + advh;
            a = a > 0.f ? a : NEG_SLOPE * a;
        }
        float w = __expf(a);
        den += w;
#pragma unroll
        for (int m = 0; m < 8; m++) {
            int k = 2 * m + half;
            int s = __shfl(sreg, k);
            float wk = __shfl(w, hc16 + k);
            uint2 v = XW2[(size_t)s * 32 + u];
            a0 += wk * __uint_as_float(v.x << 16);
            a1 += wk * __uint_as_float(v.x & 0xffff0000u);
            a2 += wk * __uint_as_float(v.y << 16);
            a3 += wk * __uint_as_float(v.y & 0xffff0000u);
        }
    }
    int cnt = end - i;
    if (cnt > 0) {
        float w = 0.f; int sreg = 0;
        if (j < cnt) {
            int i0 = i + j;
            sreg = csr_se[i0].x;
            float a = alpha_arr[(size_t)i0 * 4 + h];
            if (MODE == 0) {
                a += as2[(size_t)sreg * 4 + h] + advh;
                a = a > 0.f ? a : NEG_SLOPE * a;
            }
            w = __expf(a);
        }
        den += w;
        for (int k0 = 0; k0 < cnt; k0 += 4) {
#pragma unroll
            for (int mm = 0; mm < 2; mm++) {
                int k = k0 + 2 * mm + half;
                int kc = k & 15;
                int s = __shfl(sreg, kc);
                float wk = __shfl(w, hc16 + kc);
                if (k >= cnt) wk = 0.f;
                uint2 v = XW2[(size_t)s * 32 + u];
                a0 += wk * __uint_as_float(v.x << 16);
                a1 += wk * __uint_as_float(v.x & 0xffff0000u);
                a2 += wk * __uint_as_float(v.y << 16);
                a3 += wk * __uint_as_float(v.y & 0xffff0000u);
            }
        }
    }
    a0 += __shfl_xor(a0, 32);
    a1 += __shfl_xor(a1, 32);
    a2 += __shfl_xor(a2, 32);
    a3 += __shfl_xor(a3, 32);
    den += __shfl_xor(den, 1);
    den += __shfl_xor(den, 2);
    den += __shfl_xor(den, 4);
    den += __shfl_xor(den, 8);
    float denc = __shfl(den, hc16);
    float inv = 1.f / (denc + 1e-16f);
    if (half == 0) {
        int c0 = u * 4;
        float o0 = a0 * inv, o1 = a1 * inv, o2 = a2 * inv, o3 = a3 * inv;
        if (MODE == 1) {
            float4 bb = *(const float4*)(bias + c0);
            o0 = fmaxf(o0 + bb.x, 0.f);
            o1 = fmaxf(o1 + bb.y, 0.f);
            o2 = fmaxf(o2 + bb.z, 0.f);
            o3 = fmaxf(o3 + bb.w, 0.f);
        }
        uint2 pv;
        pv.x = pk2bf16(o0, o1);
        pv.y = pk2bf16(o2, o3);
        *((uint2*)OUT + (size_t)d * 32 + u) = pv;
    }
}

// ---------------------------------------------------------------------------
#define POOL_SPLITS 8
__global__ __launch_bounds__(256) void pool_kernel(const unsigned int* __restrict__ B,
                                                   const int* __restrict__ gstart,
                                                   float* __restrict__ pooled) {
    int g = blockIdx.x / POOL_SPLITS, sp = blockIdx.x % POOL_SPLITS;
    int lo = gstart[g], hi = gstart[g + 1];
    int cnt = hi - lo;
    int per = (cnt + POOL_SPLITS - 1) / POOL_SPLITS;
    int s0 = lo + sp * per;
    int s1 = min(s0 + per, hi);
    int jj = threadIdx.x & 15, rl = threadIdx.x >> 4;
    float ax = 0.f, ay = 0.f;
    for (int node = s0 + rl; node < s1; node += 16) {
        const unsigned int* r = B + (size_t)node * 64;
#pragma unroll
        for (int h = 0; h < 4; h++) {
            unsigned int v = r[h * 16 + jj];
            ax += __uint_as_float(v << 16);
            ay += __uint_as_float(v & 0xffff0000u);
        }
    }
    __shared__ float redx[16][16], redy[16][16];
    redx[rl][jj] = ax * 0.25f;
    redy[rl][jj] = ay * 0.25f;
    __syncthreads();
    if (threadIdx.x < 16) {
        float sx = 0.f, sy = 0.f;
#pragma unroll
        for (int i = 0; i < 16; i++) { sx += redx[i][threadIdx.x]; sy += redy[i][threadIdx.x]; }
        atomicAdd(&pooled[g * 32 + 2 * threadIdx.x], sx);
        atomicAdd(&pooled[g * 32 + 2 * threadIdx.x + 1], sy);
    }
}

__global__ void mlp_kernel(const float* __restrict__ pooled, const int* __restrict__ gstart,
                           const float* __restrict__ b2,
                           const float* __restrict__ W3, const float* __restrict__ b3,
                           const float* __restrict__ W4, const float* __restrict__ b4,
                           float* __restrict__ out) {
    int g = blockIdx.x;
    int c = threadIdx.x;
    __shared__ float pm[32];
    __shared__ float t[32];
    int cnt = gstart[g + 1] - gstart[g];
    if (c < 32) {
        float m = 0.f;
        if (cnt > 0) m = pooled[g * 32 + c] / (float)cnt + b2[c];
        pm[c] = m;
    }
    __syncthreads();
    if (c < 32) {
        float s = b3[c];
        for (int k = 0; k < 32; k++) s += pm[k] * W3[k * 32 + c];
        t[c] = fmaxf(s, 0.f);
    }
    __syncthreads();
    if (c < 2) {
        float o = b4[c];
        for (int k = 0; k < 32; k++) o += t[k] * W4[k * 2 + c];
        out[g * 2 + c] = o;
    }
}

// ---------------------------------------------------------------------------
extern "C" void kernel_launch(void* const* d_in, const int* in_sizes, int n_in,
                              void* d_out, int out_size, void* d_ws, size_t ws_size,
                              hipStream_t stream) {
    const float* x    = (const float*)d_in[0];
    const int*   eidx = (const int*)d_in[1];
    const float* ea   = (const float*)d_in[2];
    const int*   batch= (const int*)d_in[3];
    const float* W1   = (const float*)d_in[4];
    const float* as1  = (const float*)d_in[5];
    const float* ad1  = (const float*)d_in[6];
    const float* We1  = (const float*)d_in[7];
    const float* ate1 = (const float*)d_in[8];
    const float* b1   = (const float*)d_in[9];
    const float* W2   = (const float*)d_in[10];
    const float* as2  = (const float*)d_in[11];
    const float* ad2  = (const float*)d_in[12];
    const float* We2  = (const float*)d_in[13];
    const float* ate2 = (const float*)d_in[14];
    const float* b2   = (const float*)d_in[15];
    const float* W3   = (const float*)d_in[16];
    const float* b3   = (const float*)d_in[17];
    const float* W4   = (const float*)d_in[18];
    const float* b4   = (const float*)d_in[19];

    const int N_ = in_sizes[0] / 128;
    const int E_ = in_sizes[1] / 2;
    const int EN = E_ + N_;
    const int* srcp = eidx;
    const int* dstp = eidx + E_;
    const int npb = (N_ + BINB - 1) / BINB;
    const int nbk = (EN + BIN_CHUNK - 1) / BIN_CHUNK;

    char* w = (char*)d_ws;
    size_t off = 0;
    auto alloc = [&](size_t bytes) -> void* {
        void* p = w + off;
        off = (off + bytes + 255) & ~(size_t)255;
        return p;
    };
    unsigned short* A   = (unsigned short*)alloc((size_t)N_ * 128 * 2);
    unsigned short* Bb16= (unsigned short*)alloc((size_t)N_ * 128 * 2);
    float* csr_alpha = (float*)alloc((size_t)EN * 16);
    float* aeb2      = (float*)alloc((size_t)EN * 16);
    int2*  csr_se    = (int2*)alloc((size_t)EN * 8);
    int*   row_of    = (int*)alloc((size_t)EN * 4);
    int2*  bin_se    = (int2*)alloc((size_t)EN * 8);
    int*   rowptr    = (int*)alloc((size_t)(N_ + 1) * 4);
    int*   bucket_cnt= (int*)alloc(BINB * 4);
    int*   bucket_off= (int*)alloc(BINB * 4);
    int*   blockbase = (int*)alloc((size_t)nbk * BINB * 4);
    unsigned short* Wt1g = (unsigned short*)alloc(16384 * 2);
    unsigned short* Wt2g = (unsigned short*)alloc(16384 * 2);
    float* a_s       = (float*)alloc((size_t)N_ * 16);
    float* a_d       = (float*)alloc((size_t)N_ * 16);
    float* ea_sums   = (float*)alloc(64);
    float* V1        = (float*)alloc(256);
    float* V2        = (float*)alloc(256);
    float* aes1      = (float*)alloc(16);
    float* aes2      = (float*)alloc(16);
    float* pooled    = (float*)alloc(64 * 32 * 4);
    int*   gstart    = (int*)alloc(65 * 4);

    init_kernel<<<1, 256, 0, stream>>>(bucket_cnt, ea_sums, pooled);
    ea_colsum<<<1024, 256, 0, stream>>>(ea, ea_sums, E_);
    bin_count<<<nbk, 256, 0, stream>>>(dstp, bucket_cnt, blockbase, E_, EN, npb);
    bucket_scan<<<1, BINB, 0, stream>>>(bucket_cnt, bucket_off, rowptr, N_, EN);
    wprep<<<66, 256, 0, stream>>>(W1, W2, We1, ate1, We2, ate2, ea_sums,
                                  1.0f / (float)E_, Wt1g, Wt2g, V1, V2, aes1, aes2,
                                  batch, gstart, N_);
    bin_scatter<<<nbk, 256, 0, stream>>>(srcp, dstp, bucket_off, blockbase,
                                         bin_se, E_, EN, npb);
    csr_build<<<BINB, 256, 0, stream>>>(bucket_off, bin_se,
                                        csr_se, row_of, rowptr, N_, EN, npb);

    int gblk = (N_ + 63) / 64;

    // ---- layer 1 ----
    gemm_att_mfma<false><<<gblk, 256, 0, stream>>>(x, Wt1g, as1, ad1, A, a_s, a_d, N_);
    alpha1_fused<<<(EN + 255) / 256, 256, 0, stream>>>(csr_se, row_of, ea, V1, V2,
                                                       aes1, aes2, a_s, a_d,
                                                       csr_alpha, aeb2, E_, EN);
    dst_aggregate<1><<<(N_ + 3) / 4, 256, 0, stream>>>(rowptr, csr_se, csr_alpha,
                                                       nullptr, nullptr,
                                                       (const uint2*)A, b1,
                                                       (unsigned int*)Bb16, N_);

    // ---- layer 2 ----
    gemm_att_mfma<true><<<gblk, 256, 0, stream>>>(Bb16, Wt2g, as2, ad2, A, a_s, a_d, N_);
    dst_aggregate<0><<<(N_ + 3) / 4, 256, 0, stream>>>(rowptr, csr_se, aeb2,
                                                       a_s, a_d,
                                                       (const uint2*)A, b2,
                                                       (unsigned int*)Bb16, N_);
    pool_kernel<<<64 * POOL_SPLITS, 256, 0, stream>>>((const unsigned int*)Bb16,
                                                      gstart, pooled);

    // ---- graph MLP ----
    mlp_kernel<<<64, 64, 0, stream>>>(pooled, gstart, b2, W3, b3, W4, b4, (float*)d_out);
}